// Round 1
// baseline (626.554 us; speedup 1.0000x reference)
//
#include <hip/hip_runtime.h>

// NLinearMemoryEfficient: out[b,n,o] = sum_i x[b,n,i]*W[n,o,i] + bias[n,o]
// B=8192, N=256, D_IN=64, D_OUT=128, all fp32.
//
// Strategy: 256 independent small GEMMs (one per n). Block = 256 threads
// handles one n and a 256-row slab of B. W_n (32KB) staged once in LDS in
// i-vectorized layout w4[k][o] (k = i/4), x staged in 32-row tiles x4[k][r].
// Each thread computes 4 rows x 4 strided cols with float4 dot products.
// Conflict-free ds_read_b128: consecutive lanes read consecutive 16B segments.

constexpr int D_IN4 = 16;      // 64 / 4
constexpr int ROWS_PER_BLOCK = 256;
constexpr int TILE_ROWS = 32;

__global__ __launch_bounds__(256, 3) void nlinear_f32_kernel(
    const float* __restrict__ x, const float4* __restrict__ Wg,
    const float* __restrict__ bias, float* __restrict__ out)
{
    // W: [16][128] float4, o-stride padded to 129 to de-conflict staging writes
    __shared__ float4 w4[D_IN4][129];   // 33024 B
    // x tile: [16][32] float4, padded to 33
    __shared__ float4 x4[D_IN4][33];    //  8448 B

    const int bx  = blockIdx.x;
    const int n   = bx >> 5;        // 256 n values
    const int bt  = bx & 31;        // 32 slabs of 256 rows
    const int b0  = bt * ROWS_PER_BLOCK;
    const int tid = threadIdx.x;
    const int l   = tid & 31;       // col lane: o in {l, l+32, l+64, l+96}
    const int rg  = tid >> 5;       // row group 0..7 -> rows rg*4 .. rg*4+3

    // bias -> registers (reused for all row tiles)
    float bias_r[4];
#pragma unroll
    for (int c = 0; c < 4; ++c) bias_r[c] = bias[n * 128 + l + 32 * c];

    // ---- stage W_n: 128 rows x 16 float4, coalesced global reads ----
    const float4* Wn = Wg + (size_t)n * 128 * D_IN4;
#pragma unroll
    for (int p = 0; p < 8; ++p) {
        int idx = p * 256 + tid;        // idx = o*16 + k
        int o = idx >> 4, k = idx & 15;
        w4[k][o] = Wn[idx];
    }

    const float4* Xg = (const float4*)x;

    for (int t = 0; t < ROWS_PER_BLOCK / TILE_ROWS; ++t) {
        const int rowbase = b0 + t * TILE_ROWS;

        __syncthreads();   // protect x4 from previous iteration's readers
#pragma unroll
        for (int p = 0; p < 2; ++p) {
            int idx = p * 256 + tid;    // idx = r*16 + k
            int r = idx >> 4, k = idx & 15;
            x4[k][r] = Xg[((size_t)(rowbase + r) * 256 + n) * D_IN4 + k];
        }
        __syncthreads();

        float acc[4][4];
#pragma unroll
        for (int r = 0; r < 4; ++r)
#pragma unroll
            for (int c = 0; c < 4; ++c) acc[r][c] = bias_r[c];

#pragma unroll
        for (int k = 0; k < D_IN4; ++k) {
            float4 xv[4], wv[4];
#pragma unroll
            for (int r = 0; r < 4; ++r) xv[r] = x4[k][rg * 4 + r];
#pragma unroll
            for (int c = 0; c < 4; ++c) wv[c] = w4[k][l + 32 * c];
#pragma unroll
            for (int r = 0; r < 4; ++r)
#pragma unroll
                for (int c = 0; c < 4; ++c) {
                    acc[r][c] += xv[r].x * wv[c].x + xv[r].y * wv[c].y
                               + xv[r].z * wv[c].z + xv[r].w * wv[c].w;
                }
        }

        // store: per row, half-wave writes 128B contiguous segments
#pragma unroll
        for (int r = 0; r < 4; ++r) {
            size_t ob = ((size_t)(rowbase + rg * 4 + r) * 256 + n) * 128;
#pragma unroll
            for (int c = 0; c < 4; ++c) out[ob + l + 32 * c] = acc[r][c];
        }
    }
}

extern "C" void kernel_launch(void* const* d_in, const int* in_sizes, int n_in,
                              void* d_out, int out_size, void* d_ws, size_t ws_size,
                              hipStream_t stream) {
    const float*  xp = (const float*)d_in[0];
    const float4* Wp = (const float4*)d_in[1];
    const float*  bp = (const float*)d_in[2];
    float* op = (float*)d_out;

    dim3 grid(256 * 32);   // n * row-slabs
    dim3 block(256);
    hipLaunchKernelGGL(nlinear_f32_kernel, grid, block, 0, stream, xp, Wp, bp, op);
}

// Round 2
// 396.395 us; speedup vs baseline: 1.5806x; 1.5806x over previous
//
#include <hip/hip_runtime.h>

// NLinearMemoryEfficient: out[b,n,o] = sum_i x[b,n,i]*W[n,o,i] + bias[n,o]
// B=8192, N=256, D_IN=64, D_OUT=128, fp32 in/out.
//
// bf16 MFMA path (threshold 7.09e-2, expected absmax ~5e-3):
//  - block = 256 threads (4 waves), one n, 128-row slab. grid = 256*64.
//  - W_n converted f32->bf16 (RNE) once per block, staged in LDS in
//    B-fragment-packed order: ds_read_b128 at lane*16 -> conflict-free.
//  - x loaded as float4 pairs from global, converted to A-fragments in regs.
//  - k-slot mapping k = ks*32 + (lane>>4)*8 + j used identically for A and B
//    (any consistent per-lane k bijection is valid for MFMA).
//  - C/D layout (verified): col = lane&15, row = (lane>>4)*4 + reg.
//  - bias folded into accumulator init; single __syncthreads per block.

typedef short short8 __attribute__((ext_vector_type(8)));
typedef float float4v __attribute__((ext_vector_type(4)));
typedef unsigned int uint4v __attribute__((ext_vector_type(4)));

constexpr int NFEAT = 256;
constexpr int DI    = 64;
constexpr int DO    = 128;
constexpr int BROWS = 128;   // rows per block

__device__ __forceinline__ uint32_t pack_bf16(float a, float b) {
    uint32_t ua = __builtin_bit_cast(uint32_t, a);
    uint32_t ub = __builtin_bit_cast(uint32_t, b);
    ua += 0x7fffu + ((ua >> 16) & 1u);   // round-to-nearest-even
    ub += 0x7fffu + ((ub >> 16) & 1u);
    return (ua >> 16) | (ub & 0xffff0000u);
}

__global__ __launch_bounds__(256, 4) void nlinear_mfma_kernel(
    const float* __restrict__ x, const float* __restrict__ W,
    const float* __restrict__ bias, float* __restrict__ out)
{
    // [ct][ks][lane][slot]: B-fragment for col-tile ct, k-step ks. 16 KB.
    __shared__ uint32_t wfrag[8][2][64][4];

    // XCD-aware bijective swizzle: 16384 blocks, 8 XCDs -> contiguous 2048
    // blocks (32 n values) per XCD; W working set 1 MB per L2.
    const int bid  = blockIdx.x;
    const int swz  = (bid & 7) * 2048 + (bid >> 3);
    const int n    = swz >> 6;        // 256 n's
    const int slab = swz & 63;        // 64 slabs of 128 rows

    const int t   = threadIdx.x;
    const int l   = t & 63;
    const int wv  = t >> 6;
    const int llo = l & 15;
    const int lhi = l >> 4;

    // ---- stage W_n as bf16 B-fragments in LDS ----
    // element (o, i): ct=o>>4, lane=((i>>3)&3)*16 | (o&15), ks=i>>5, slot=(i>>1)&3
    const float4* Wn4 = (const float4*)(W + (size_t)n * DO * DI);
#pragma unroll
    for (int it = 0; it < 8; ++it) {
        int idx = it * 256 + t;          // float4 index; o = idx/16, i0 = (idx%16)*4
        float4 f = Wn4[idx];
        int o  = idx >> 4;
        int p  = idx & 15;
        int ct   = o >> 4;
        int lane = (((p >> 1) & 3) << 4) | (o & 15);
        int ks   = p >> 3;
        int slot = (p & 1) * 2;          // even -> 8B-aligned pair write
        uint2 pk = make_uint2(pack_bf16(f.x, f.y), pack_bf16(f.z, f.w));
        *(uint2*)&wfrag[ct][ks][lane][slot] = pk;
    }

    // bias per col-tile (col = ct*16 + llo), folded into acc init
    float bias_r[8];
#pragma unroll
    for (int ct = 0; ct < 8; ++ct) bias_r[ct] = bias[n * DO + ct * 16 + llo];

    // ---- A fragments: 2 row-tiles x 2 k-steps, direct from global ----
    const int r0 = slab * BROWS + wv * 32;
    short8 a[2][2];
#pragma unroll
    for (int rt = 0; rt < 2; ++rt) {
        const size_t rowbase = ((size_t)(r0 + rt * 16 + llo) * NFEAT + n) * DI;
#pragma unroll
        for (int ks = 0; ks < 2; ++ks) {
            const float4* px = (const float4*)(x + rowbase + ks * 32 + lhi * 8);
            float4 f0 = px[0];
            float4 f1 = px[1];
            uint4v u = { pack_bf16(f0.x, f0.y), pack_bf16(f0.z, f0.w),
                         pack_bf16(f1.x, f1.y), pack_bf16(f1.z, f1.w) };
            a[rt][ks] = __builtin_bit_cast(short8, u);
        }
    }

    float4v acc[2][8];
#pragma unroll
    for (int rt = 0; rt < 2; ++rt)
#pragma unroll
        for (int ct = 0; ct < 8; ++ct) {
            float bv = bias_r[ct];
            acc[rt][ct] = (float4v){bv, bv, bv, bv};
        }

    __syncthreads();   // wfrag ready

#pragma unroll
    for (int ct = 0; ct < 8; ++ct) {
        short8 b0 = ((const short8*)&wfrag[ct][0][0][0])[l];  // conflict-free b128
        short8 b1 = ((const short8*)&wfrag[ct][1][0][0])[l];
#pragma unroll
        for (int rt = 0; rt < 2; ++rt) {
            acc[rt][ct] = __builtin_amdgcn_mfma_f32_16x16x32_bf16(a[rt][0], b0, acc[rt][ct], 0, 0, 0);
            acc[rt][ct] = __builtin_amdgcn_mfma_f32_16x16x32_bf16(a[rt][1], b1, acc[rt][ct], 0, 0, 0);
        }
    }

    // ---- store: row = r0 + rt*16 + lhi*4 + reg, col = ct*16 + llo ----
#pragma unroll
    for (int rt = 0; rt < 2; ++rt) {
#pragma unroll
        for (int reg = 0; reg < 4; ++reg) {
            const size_t rowb = ((size_t)(r0 + rt * 16 + lhi * 4 + reg) * NFEAT + n) * DO + llo;
#pragma unroll
            for (int ct = 0; ct < 8; ++ct) {
                out[rowb + ct * 16] = acc[rt][ct][reg];
            }
        }
    }
}

extern "C" void kernel_launch(void* const* d_in, const int* in_sizes, int n_in,
                              void* d_out, int out_size, void* d_ws, size_t ws_size,
                              hipStream_t stream) {
    const float* xp = (const float*)d_in[0];
    const float* Wp = (const float*)d_in[1];
    const float* bp = (const float*)d_in[2];
    float* op = (float*)d_out;

    dim3 grid(256 * 64);   // n * slabs(128 rows)
    dim3 block(256);
    hipLaunchKernelGGL(nlinear_mfma_kernel, grid, block, 0, stream, xp, Wp, bp, op);
}

// Round 3
// 361.557 us; speedup vs baseline: 1.7329x; 1.0964x over previous
//
#include <hip/hip_runtime.h>

// NLinearMemoryEfficient: out[b,n,o] = sum_i x[b,n,i]*W[n,o,i] + bias[n,o]
// B=8192, N=256, D_IN=64, D_OUT=128, fp32 in/out. bf16 MFMA (thr 7.09e-2).
//
// Transposed-role MFMA: A = W (rows = o), B = x (cols = b) so that D's 4
// accumulator regs are 4 CONSECUTIVE o values -> one float4 store per lane.
// Block = 256 thr (4 waves, 2x2), one n, loops S=8 tiles of 128 b-rows.
//  - W_n packed once into LDS A-frag layout (16 KB).
//  - x staged per tile: fully COALESCED global float4 loads (lane = i-chunk),
//    packed to bf16 B-frag layout in LDS (16 KB x 2, double-buffered).
//  - Pipeline: issue tile j+1 global loads BEFORE tile j's MFMA (latency
//    hides under compute+stores), pack+ds_write after, ONE barrier per tile.
//  - Frag reads: addr = lane*16B -> uniform bank groups, conflict-free.
//  - Bias used as the C operand of the ks=0 MFMA (no acc-init movs).
//  - C/D layout (verified r2): col=lane&15 (=b), row=(lane>>4)*4+reg (=o).

typedef short  short8  __attribute__((ext_vector_type(8)));
typedef float  float4v __attribute__((ext_vector_type(4)));

constexpr int NFEAT  = 256;
constexpr int DI     = 64;
constexpr int DO     = 128;
constexpr int TILE_B = 128;
constexpr int S      = 8;     // row-tiles per block

__device__ __forceinline__ uint32_t pack_bf16(float a, float b) {
    uint32_t ua = __builtin_bit_cast(uint32_t, a);
    uint32_t ub = __builtin_bit_cast(uint32_t, b);
    ua += 0x7fffu + ((ua >> 16) & 1u);   // RNE
    ub += 0x7fffu + ((ub >> 16) & 1u);
    return (ua >> 16) | (ub & 0xffff0000u);
}

__global__ __launch_bounds__(256, 3) void nlinear_mfma_t_kernel(
    const float* __restrict__ x, const float* __restrict__ W,
    const float* __restrict__ bias, float* __restrict__ out)
{
    // frag layout: [tile16][ks][lane][slot] u32; element k = ks*32+lhi*8+j
    __shared__ __align__(16) uint32_t wfrag[8][2][64][4];     // 16 KB (o-tiles)
    __shared__ __align__(16) uint32_t xfrag[2][8][2][64][4];  // 32 KB (b-tiles, dbuf)

    // XCD swizzle: 2048 blocks, 8 XCDs -> 32 consecutive n per XCD.
    const int bid  = blockIdx.x;
    const int swz  = (bid & 7) * 256 + (bid >> 3);
    const int n    = swz >> 3;         // 0..255
    const int slab = swz & 7;          // 8 slabs of S*128 = 1024 rows
    const int b_base = slab * (TILE_B * S);

    const int t   = threadIdx.x;
    const int l   = t & 63;
    const int wv  = t >> 6;
    const int wr  = wv >> 1;           // b-half   (0..1)
    const int wc  = wv & 1;            // o-half   (0..1)
    const int llo = l & 15;
    const int lhi = l >> 4;

    // ---- stage W_n as bf16 A-fragments (rows = o) ----
    const float4* Wn4 = (const float4*)(W + (size_t)n * DO * DI);
#pragma unroll
    for (int p = 0; p < 8; ++p) {
        int idx  = p * 256 + t;              // f4 idx: o = idx>>4, i0 = (idx&15)*4
        float4 f = Wn4[idx];
        int lane = (((idx >> 1) & 3) << 4) | (t >> 4);  // lhi=(i0>>3)&3, o&15
        int ks   = (idx >> 3) & 1;
        int sp   = (idx & 1) * 2;
        uint2 pk = make_uint2(pack_bf16(f.x, f.y), pack_bf16(f.z, f.w));
        *(uint2*)&wfrag[p][ks][lane][sp] = pk;
    }

    // bias: per lane 4 consecutive o -> C operand of ks=0 MFMA
    float4v bias4[4];
#pragma unroll
    for (int ot = 0; ot < 4; ++ot)
        bias4[ot] = *(const float4v*)&bias[n * DO + wc * 64 + ot * 16 + lhi * 4];

    const float4* Xg4 = (const float4*)x;
    float4 xr[8];

    // ---- load x tile 0 (coalesced: lane = 16B chunk within b-row) ----
#pragma unroll
    for (int p = 0; p < 8; ++p) {
        int idx = p * 256 + t;               // b = idx>>4, chunk = idx&15
        uint32_t b = b_base + (idx >> 4);
        xr[p] = Xg4[b * 4096u + n * 16u + (idx & 15)];
    }
    // pack to B-frag layout, buffer 0
#pragma unroll
    for (int p = 0; p < 8; ++p) {
        int idx  = p * 256 + t;
        int lane = (((idx >> 1) & 3) << 4) | (t >> 4);
        int ks   = (idx >> 3) & 1;
        int sp   = (idx & 1) * 2;
        uint2 pk = make_uint2(pack_bf16(xr[p].x, xr[p].y), pack_bf16(xr[p].z, xr[p].w));
        *(uint2*)&xfrag[0][p][ks][lane][sp] = pk;
    }
    __syncthreads();

    for (int j = 0; j < S; ++j) {
        const int cur = j & 1;

        // issue next tile's global loads early (hide under MFMA+stores)
        if (j < S - 1) {
#pragma unroll
            for (int p = 0; p < 8; ++p) {
                int idx = p * 256 + t;
                uint32_t b = b_base + (j + 1) * TILE_B + (idx >> 4);
                xr[p] = Xg4[b * 4096u + n * 16u + (idx & 15)];
            }
        }

        // ---- compute: D(o,b) = W_n * x^T + bias ----
        float4v acc[4][4];
#pragma unroll
        for (int ks = 0; ks < 2; ++ks) {
            short8 wf[4];
#pragma unroll
            for (int ot = 0; ot < 4; ++ot)
                wf[ot] = *(const short8*)&wfrag[wc * 4 + ot][ks][l][0];
#pragma unroll
            for (int bt = 0; bt < 4; ++bt) {
                short8 xf = *(const short8*)&xfrag[cur][wr * 4 + bt][ks][l][0];
#pragma unroll
                for (int ot = 0; ot < 4; ++ot) {
                    acc[bt][ot] = __builtin_amdgcn_mfma_f32_16x16x32_bf16(
                        wf[ot], xf, (ks == 0) ? bias4[ot] : acc[bt][ot], 0, 0, 0);
                }
            }
        }

        // ---- store: lane -> (b = col, o = lhi*4+reg) => float4 per (bt,ot) ----
#pragma unroll
        for (int bt = 0; bt < 4; ++bt) {
            uint32_t b = b_base + j * TILE_B + wr * 64 + bt * 16 + llo;
            uint32_t off = b * 32768u + n * 128u + wc * 64u + lhi * 4u;
#pragma unroll
            for (int ot = 0; ot < 4; ++ot)
                *(float4v*)&out[off + ot * 16u] = acc[bt][ot];
        }

        // pack + write next tile's fragments into the other buffer
        if (j < S - 1) {
#pragma unroll
            for (int p = 0; p < 8; ++p) {
                int idx  = p * 256 + t;
                int lane = (((idx >> 1) & 3) << 4) | (t >> 4);
                int ks   = (idx >> 3) & 1;
                int sp   = (idx & 1) * 2;
                uint2 pk = make_uint2(pack_bf16(xr[p].x, xr[p].y),
                                      pack_bf16(xr[p].z, xr[p].w));
                *(uint2*)&xfrag[1 - cur][p][ks][lane][sp] = pk;
            }
        }
        __syncthreads();
    }
}

extern "C" void kernel_launch(void* const* d_in, const int* in_sizes, int n_in,
                              void* d_out, int out_size, void* d_ws, size_t ws_size,
                              hipStream_t stream) {
    const float* xp = (const float*)d_in[0];
    const float* Wp = (const float*)d_in[1];
    const float* bp = (const float*)d_in[2];
    float* op = (float*)d_out;

    dim3 grid(256 * 8);    // n * slabs(1024 rows)
    dim3 block(256);
    hipLaunchKernelGGL(nlinear_mfma_t_kernel, grid, block, 0, stream, xp, Wp, bp, op);
}